// Round 20
// baseline (268.750 us; speedup 1.0000x reference)
//
#include <hip/hip_runtime.h>
#include <hip/hip_bf16.h>

#define DM 256
#define NB 128
#define SQ 384
#define SK 384

typedef __bf16 bf16x4 __attribute__((ext_vector_type(4)));
typedef __bf16 bf16x8 __attribute__((ext_vector_type(8)));
typedef float f32x4 __attribute__((ext_vector_type(4)));
typedef unsigned short u16;
typedef unsigned int u32;

union BF8 { bf16x8 v8; bf16x4 v4[2]; uint2 u2[2]; };

__device__ __forceinline__ u16 f2bf(float f) {
    union { float fv; u32 u; } v; v.fv = f;
    u32 r = v.u + 0x7FFFu + ((v.u >> 16) & 1u);
    return (u16)(r >> 16);
}
__device__ __forceinline__ float bf2f(u16 u) {
    union { u32 v; float f; } x; x.v = ((u32)u) << 16; return x.f;
}
__device__ __forceinline__ uint2 pack4(float a, float b, float c, float d) {
    uint2 r;
    r.x = (u32)f2bf(a) | ((u32)f2bf(b) << 16);
    r.y = (u32)f2bf(c) | ((u32)f2bf(d) << 16);
    return r;
}
__device__ __forceinline__ uint2 pack4c(f32x4 v) {
    bf16x4 t;
    t[0] = (__bf16)v[0]; t[1] = (__bf16)v[1];
    t[2] = (__bf16)v[2]; t[3] = (__bf16)v[3];
    union { bf16x4 b; uint2 u; } cv; cv.b = t; return cv.u;
}
// async global->LDS, 16B per lane; LDS dest = wave-uniform base + lane*16
__device__ __forceinline__ void glds16(const void* g, void* l) {
    __builtin_amdgcn_global_load_lds(
        (const __attribute__((address_space(1))) unsigned int*)g,
        (__attribute__((address_space(3))) unsigned int*)l, 16, 0, 0);
}

// ---------------------------------------------------------------------------
// stage_W_fp32: stage one Wt slab [64 n][256 k] into swizzled LDS directly
// from fp32 W[k][n] (transpose + bf16 in registers). Write pattern matches
// the proven bf16 stager half-for-half: lo 8B (k 0-3 of chunk) at pa2^swz,
// hi 8B (k 4-7) at (pa2+16)^swz -> fragment reads stay 16B contiguous.
// 512 tasks = 32 k-chunks x 16 n-quads; 2 tasks/thread.
// ---------------------------------------------------------------------------
__device__ __forceinline__ void stage_W_fp32(u16* Wlds, const float* __restrict__ Wsrc,
                                             int n0, int tid) {
#pragma unroll
    for (int it = 0; it < 2; ++it) {
        int task = tid + it * 256;
        int c8 = (task & 31) * 8;          // k-chunk start (u16 units)
        int nq4 = task >> 5;               // n-quad index 0..15
        float4 l[8];
#pragma unroll
        for (int j = 0; j < 8; ++j)
            l[j] = *(const float4*)&Wsrc[(size_t)(c8 + j) * DM + n0 + nq4 * 4];
        int within = c8 & 31;
        int pa2 = (c8 >> 5) * 64 + ((within >> 3) & 1) * 32 + (within >> 4) * 8;
#pragma unroll
        for (int i = 0; i < 4; ++i) {
            int row = nq4 * 4 + i;
            int sw = (row & 7) << 4;
            char* rb_ = (char*)Wlds + row * 512;
            uint2 lo, hi;
            lo.x = (u32)f2bf(((const float*)&l[0])[i]) | ((u32)f2bf(((const float*)&l[1])[i]) << 16);
            lo.y = (u32)f2bf(((const float*)&l[2])[i]) | ((u32)f2bf(((const float*)&l[3])[i]) << 16);
            hi.x = (u32)f2bf(((const float*)&l[4])[i]) | ((u32)f2bf(((const float*)&l[5])[i]) << 16);
            hi.y = (u32)f2bf(((const float*)&l[6])[i]) | ((u32)f2bf(((const float*)&l[7])[i]) << 16);
            *(uint2*)(rb_ + (pa2 ^ sw)) = lo;
            *(uint2*)(rb_ + ((pa2 + 16) ^ sw)) = hi;
        }
    }
}

// ---------------------------------------------------------------------------
// proj01_kernel (R20): MERGED proj<0> + proj<1> + prep_nb; W staged DIRECTLY
// from fp32 weights (prep_w kernel deleted). q-scale applied in epilogue.
// blocks 0..383:   mode 0 (q/gate from q_data via q_w/g_w)
// blocks 384..767: mode 1 (k/v from m_data via k_w/v_w, permuted outputs)
// blocks 768..1055: nb2 = nbias*log2e - 20 (elementwise tail)
// ---------------------------------------------------------------------------
__global__ __launch_bounds__(256)
void proj01_kernel(const float* __restrict__ Aq, const float* __restrict__ Am,
                   const float* __restrict__ q_w, const float* __restrict__ g_w,
                   const float* __restrict__ k_w, const float* __restrict__ v_w,
                   const float* __restrict__ gb, const float* __restrict__ nbias,
                   u16* __restrict__ qb, u16* __restrict__ gateb,
                   u16* __restrict__ kb, u16* __restrict__ vT,
                   float* __restrict__ nb2)
{
    const int bx = blockIdx.x;
    const int tid = threadIdx.x;
    if (bx >= 768) {
        const size_t base = ((size_t)(bx - 768) * 256 + tid) * 16;
#pragma unroll
        for (int i = 0; i < 4; ++i) {
            f32x4 v = *(const f32x4*)&nbias[base + i * 4];
            *(f32x4*)&nb2[base + i * 4] = v * 1.4426950408889634f - 20.0f;
        }
        return;
    }
    const int mode = bx >= 384;
    const int m0 = (mode ? bx - 384 : bx) * 128;
    const float* Af = mode ? Am : Aq;
    const float* W1 = mode ? k_w : q_w;
    const float* W2 = mode ? v_w : g_w;
    const float QSCALE = (float)(0.17677669529663687 * 1.4426950408889634);

    __shared__ u16 Wlds[64 * 256];
    const int lane = tid & 63, w = tid >> 6;
    const int lr = lane & 15, lg = lane >> 4;

    BF8 af0[8], af1[8];
    {
        const float* ar0 = Af + (size_t)(m0 + w * 16 + lr) * DM + 4 * lg;
        const float* ar1 = ar0 + (size_t)64 * DM;
#pragma unroll
        for (int ks = 0; ks < 8; ++ks) {
            f32x4 v0 = *(const f32x4*)&ar0[ks * 32];
            f32x4 v1 = *(const f32x4*)&ar0[ks * 32 + 16];
            af0[ks].u2[0] = pack4(v0[0], v0[1], v0[2], v0[3]);
            af0[ks].u2[1] = pack4(v1[0], v1[1], v1[2], v1[3]);
            f32x4 w0 = *(const f32x4*)&ar1[ks * 32];
            f32x4 w1 = *(const f32x4*)&ar1[ks * 32 + 16];
            af1[ks].u2[0] = pack4(w0[0], w0[1], w0[2], w0[3]);
            af1[ks].u2[1] = pack4(w1[0], w1[1], w1[2], w1[3]);
        }
    }

    for (int sl = 0; sl < 8; ++sl) {
        const float* Wsrc = (sl < 4) ? W1 : W2;
        const int n0 = (sl & 3) * 64;
        if (sl) __syncthreads();
        stage_W_fp32(Wlds, Wsrc, n0, tid);
        __syncthreads();

        f32x4 acc0[4], acc1[4];
#pragma unroll
        for (int nf = 0; nf < 4; ++nf) {
            acc0[nf] = (f32x4){0.f, 0.f, 0.f, 0.f};
            acc1[nf] = (f32x4){0.f, 0.f, 0.f, 0.f};
        }
#pragma unroll
        for (int ks = 0; ks < 8; ++ks) {
#pragma unroll
            for (int nf = 0; nf < 4; ++nf) {
                int row = nf * 16 + lr;
                bf16x8 bfr = *(const bf16x8*)((char*)Wlds + row * 512 +
                                              ((ks * 64 + lg * 16) ^ ((row & 7) << 4)));
                acc0[nf] = __builtin_amdgcn_mfma_f32_16x16x32_bf16(af0[ks].v8, bfr, acc0[nf], 0, 0, 0);
                acc1[nf] = __builtin_amdgcn_mfma_f32_16x16x32_bf16(af1[ks].v8, bfr, acc1[nf], 0, 0, 0);
            }
        }

#pragma unroll
        for (int rg = 0; rg < 2; ++rg) {
            const int mb = m0 + rg * 64;
#pragma unroll
            for (int nf = 0; nf < 4; ++nf) {
                f32x4 accv = rg ? acc1[nf] : acc0[nf];
                int n = n0 + nf * 16 + lr;
                int gn = (sl & 3) * 64 + nf * 16 + lr;
                if (mode == 0) {
                    if (sl < 4) {
#pragma unroll
                        for (int r = 0; r < 4; ++r)
                            qb[(size_t)(mb + w * 16 + 4 * lg + r) * DM + n] = f2bf(accv[r] * QSCALE);
                    } else {
                        float gbv = gb[gn];
#pragma unroll
                        for (int r = 0; r < 4; ++r)
                            gateb[(size_t)(mb + w * 16 + 4 * lg + r) * DM + gn] =
                                f2bf(1.f / (1.f + __expf(-(accv[r] + gbv))));
                    }
                } else {
                    if (sl < 4) {
                        int pn = (n & ~31) | (((n >> 2) & 3) << 3) | (((n >> 4) & 1) << 2) | (n & 3);
#pragma unroll
                        for (int r = 0; r < 4; ++r)
                            kb[(size_t)(mb + w * 16 + 4 * lg + r) * DM + pn] = f2bf(accv[r]);
                    } else {
                        int bb = mb / SQ;
                        int kkl = mb - bb * SQ + w * 16 + 4 * lg;
                        int cc = kkl & 31;
                        int kkp = (kkl & ~31) | (((cc >> 2) & 3) << 3) | (((cc >> 4) & 1) << 2);
                        *(uint2*)&vT[(size_t)(bb * DM + gn) * SK + kkp] =
                            pack4(accv[0], accv[1], accv[2], accv[3]);
                    }
                }
            }
        }
    }
}

// ---------------------------------------------------------------------------
// out_proj (R20): out = wavg @ o_w + o_b, o_w staged directly from fp32.
// ---------------------------------------------------------------------------
__global__ __launch_bounds__(256)
void out_proj_kernel(const u16* __restrict__ Abf, const float* __restrict__ o_w,
                     const float* __restrict__ ob, float* __restrict__ outf)
{
    __shared__ u16 Wlds[64 * 256];
    const int tid = threadIdx.x, lane = tid & 63, w = tid >> 6;
    const int lr = lane & 15, lg = lane >> 4;
    const int m0 = blockIdx.x * 128;

    BF8 af0[8], af1[8];
    {
        const u16* ar0 = Abf + (size_t)(m0 + w * 16 + lr) * DM + 4 * lg;
        const u16* ar1 = ar0 + (size_t)64 * DM;
#pragma unroll
        for (int ks = 0; ks < 8; ++ks) {
            af0[ks].u2[0] = *(const uint2*)&ar0[ks * 32];
            af0[ks].u2[1] = *(const uint2*)&ar0[ks * 32 + 16];
            af1[ks].u2[0] = *(const uint2*)&ar1[ks * 32];
            af1[ks].u2[1] = *(const uint2*)&ar1[ks * 32 + 16];
        }
    }

    for (int sl = 0; sl < 4; ++sl) {
        const int n0 = sl * 64;
        if (sl) __syncthreads();
        stage_W_fp32(Wlds, o_w, n0, tid);
        __syncthreads();

        f32x4 acc0[4], acc1[4];
#pragma unroll
        for (int nf = 0; nf < 4; ++nf) {
            acc0[nf] = (f32x4){0.f, 0.f, 0.f, 0.f};
            acc1[nf] = (f32x4){0.f, 0.f, 0.f, 0.f};
        }
#pragma unroll
        for (int ks = 0; ks < 8; ++ks) {
#pragma unroll
            for (int nf = 0; nf < 4; ++nf) {
                int row = nf * 16 + lr;
                bf16x8 bfr = *(const bf16x8*)((char*)Wlds + row * 512 +
                                              ((ks * 64 + lg * 16) ^ ((row & 7) << 4)));
                acc0[nf] = __builtin_amdgcn_mfma_f32_16x16x32_bf16(af0[ks].v8, bfr, acc0[nf], 0, 0, 0);
                acc1[nf] = __builtin_amdgcn_mfma_f32_16x16x32_bf16(af1[ks].v8, bfr, acc1[nf], 0, 0, 0);
            }
        }

#pragma unroll
        for (int rg = 0; rg < 2; ++rg) {
            const int mb = m0 + rg * 64;
#pragma unroll
            for (int nf = 0; nf < 4; ++nf) {
                f32x4 accv = rg ? acc1[nf] : acc0[nf];
                int n = n0 + nf * 16 + lr;
                float obv = ob[n];
#pragma unroll
                for (int r = 0; r < 4; ++r)
                    outf[(size_t)(mb + w * 16 + 4 * lg + r) * DM + n] = accv[r] + obv;
            }
        }
    }
}

// ---------------------------------------------------------------------------
// attn (R19-exact, frozen): 256-thr blocks (4 waves = 4 heads), chunked-XCD
// swizzle, block = (qt, b, hg). Buffers K 8K + V 8K + bias 8K = 24KB, dbuf
// 48KB. gload_lds staging with source-side inverse swizzle (producer-
// permuted kb/vT), nbias first (FIFO), fixed-max exp2 softmax, deferred lsum.
// ---------------------------------------------------------------------------
__global__ __launch_bounds__(256, 1)
void attn_kernel(const u16* __restrict__ Qb, const u16* __restrict__ Kb,
                 const u16* __restrict__ vT, const u16* __restrict__ gateb,
                 const float* __restrict__ bias, const float* __restrict__ nb2,
                 u16* __restrict__ wavg)
{
    extern __shared__ char smem[];   // 2 x 24576: K 8K | V 8K | bias 8K
    const int tid = threadIdx.x, lane = tid & 63, hw = tid >> 6;
    const int lr = lane & 15, lg = lane >> 4;
    const int bid0 = blockIdx.x;
    const int bid = (bid0 & 7) * 192 + (bid0 >> 3);
    const int pair = bid >> 1, hg = bid & 1;
    const int qt = pair >> 7, b = pair & 127;   // qt-major
    const int q0 = qt * 64;
    const int h = hg * 4 + hw;
    const float LOG2E = 1.4426950408889634f;

    const int ciA = hw * 64 + lane, ciB = 256 + hw * 64 + lane;
    const int krA = ciA >> 4, kjA = (ciA & 15) ^ (krA & 7);
    const int krB = ciB >> 4, kjB = (ciB & 15) ^ (krB & 7);
    const u16* kgA = Kb + ((size_t)b * SK + krA) * DM + hg * 128 + kjA * 8;
    const u16* kgB = Kb + ((size_t)b * SK + krB) * DM + hg * 128 + kjB * 8;
    const int vrA = ciA >> 2, vjA = (ciA & 3) ^ ((vrA >> 1) & 3);
    const int vrB = ciB >> 2, vjB = (ciB & 3) ^ ((vrB >> 1) & 3);
    const u16* vgA = vT + ((size_t)b * DM + hg * 128 + vrA) * SK + vjA * 8;
    const u16* vgB = vT + ((size_t)b * DM + hg * 128 + vrB) * SK + vjB * 8;
    const int bqA = ciA >> 3, bjA = (ciA & 7) ^ (bqA & 7);
    const int bqB = ciB >> 3, bjB = (ciB & 7) ^ (bqB & 7);
    const float* bgA = bias + ((size_t)b * SQ + q0 + bqA) * SK + bjA * 4;
    const float* bgB = bias + ((size_t)b * SQ + q0 + bqB) * SK + bjB * 4;

    const int dA = hw * 1024, dB = 4096 + hw * 1024;

    BF8 qf[4];
    {
        const u16* qp = Qb + (size_t)(b * SQ + q0 + lr) * DM + h * 32 + 4 * lg;
#pragma unroll
        for (int nf = 0; nf < 4; ++nf) {
            qf[nf].u2[0] = *(const uint2*)&qp[nf * 16 * DM];
            qf[nf].u2[1] = *(const uint2*)&qp[nf * 16 * DM + 16];
        }
    }

    f32x4 Oacc[2][4];
    float lsum[4];
#pragma unroll
    for (int nf = 0; nf < 4; ++nf) {
        lsum[nf] = 0.f;
        Oacc[0][nf] = (f32x4){0.f, 0.f, 0.f, 0.f};
        Oacc[1][nf] = (f32x4){0.f, 0.f, 0.f, 0.f};
    }

    const float* np = nb2 + ((size_t)h * SQ + q0) * SK + 4 * lg;

    auto stage = [&](char* buf) {
        glds16(kgA, buf + dA); glds16(kgB, buf + dB);
        glds16(vgA, buf + 8192 + dA); glds16(vgB, buf + 8192 + dB);
        glds16(bgA, buf + 16384 + dA); glds16(bgB, buf + 16384 + dB);
        kgA += 32 * DM; kgB += 32 * DM; vgA += 32; vgB += 32; bgA += 32; bgB += 32;
    };

    stage(smem);
    asm volatile("s_waitcnt vmcnt(0)" ::: "memory");
    __builtin_amdgcn_s_barrier();

    int cur = 0;
#pragma unroll 1
    for (int kb = 0; kb < 12; ++kb) {
        const int k0 = kb * 32;
        char* buf = smem + cur * 24576;
        char* Kc = buf; char* Vc = buf + 8192; char* Bc = buf + 16384;

        f32x4 n4r[4][2];
#pragma unroll
        for (int nf = 0; nf < 4; ++nf)
#pragma unroll
            for (int rb = 0; rb < 2; ++rb)
                n4r[nf][rb] = *(const f32x4*)&np[(size_t)(nf * 16 + lr) * SK + k0 + rb * 16];
        __builtin_amdgcn_sched_barrier(0);

        if (kb < 11) stage(smem + (cur ^ 1) * 24576);

        f32x4 st[4][2];
        __builtin_amdgcn_s_setprio(1);
#pragma unroll
        for (int nf = 0; nf < 4; ++nf)
#pragma unroll
            for (int rb = 0; rb < 2; ++rb) {
                bf16x8 kfr = *(const bf16x8*)(Kc + (rb * 16 + lr) * 256 +
                                              (((hw * 4 + lg) ^ (lr & 7)) << 4));
                st[nf][rb] = __builtin_amdgcn_mfma_f32_16x16x32_bf16(
                    kfr, qf[nf].v8, (f32x4){0.f, 0.f, 0.f, 0.f}, 0, 0, 0);
            }
        __builtin_amdgcn_s_setprio(0);

        BF8 pvv[4];
#pragma unroll
        for (int nf = 0; nf < 4; ++nf)
#pragma unroll
            for (int rb = 0; rb < 2; ++rb) {
                f32x4 b4 = *(const f32x4*)(Bc + (nf * 16 + lr) * 128 +
                                           (((rb * 4 + lg) ^ (lr & 7)) << 4));
                f32x4 s = st[nf][rb] + b4 * LOG2E + n4r[nf][rb];
                f32x4 e;
                e[0] = __builtin_amdgcn_exp2f(s[0]);
                e[1] = __builtin_amdgcn_exp2f(s[1]);
                e[2] = __builtin_amdgcn_exp2f(s[2]);
                e[3] = __builtin_amdgcn_exp2f(s[3]);
                lsum[nf] += (e[0] + e[1]) + (e[2] + e[3]);
                pvv[nf].u2[rb] = pack4c(e);
            }

        __builtin_amdgcn_s_setprio(1);
#pragma unroll
        for (int cf = 0; cf < 2; ++cf) {
            int row = hw * 32 + cf * 16 + lr;
            bf16x8 vfr = *(const bf16x8*)(Vc + row * 64 + ((lg ^ ((lr >> 1) & 3)) << 4));
#pragma unroll
            for (int nf = 0; nf < 4; ++nf)
                Oacc[cf][nf] = __builtin_amdgcn_mfma_f32_16x16x32_bf16(
                    vfr, pvv[nf].v8, Oacc[cf][nf], 0, 0, 0);
        }
        __builtin_amdgcn_s_setprio(0);

        if (kb < 11) {
            asm volatile("s_waitcnt vmcnt(0)" ::: "memory");
            __builtin_amdgcn_s_barrier();
            cur ^= 1;
        }
    }

#pragma unroll
    for (int nf = 0; nf < 4; ++nf) {
        lsum[nf] += __shfl_xor(lsum[nf], 16, 64);
        lsum[nf] += __shfl_xor(lsum[nf], 32, 64);
    }

#pragma unroll
    for (int nf = 0; nf < 4; ++nf) {
        float rl = 1.0f / lsum[nf];
        size_t qrow = (size_t)(b * SQ + q0 + nf * 16 + lr);
#pragma unroll
        for (int cf = 0; cf < 2; ++cf) {
            size_t idx = qrow * DM + h * 32 + cf * 16 + 4 * lg;
            uint2 g2 = *(const uint2*)&gateb[idx];
            float g0 = bf2f((u16)(g2.x & 0xffff)), g1 = bf2f((u16)(g2.x >> 16));
            float g2f = bf2f((u16)(g2.y & 0xffff)), g3 = bf2f((u16)(g2.y >> 16));
            f32x4 o = Oacc[cf][nf];
            *(uint2*)&wavg[idx] = pack4(o[0] * rl * g0, o[1] * rl * g1,
                                        o[2] * rl * g2f, o[3] * rl * g3);
        }
    }
}

// ---------------------------------------------------------------------------
extern "C" void kernel_launch(void* const* d_in, const int* in_sizes, int n_in,
                              void* d_out, int out_size, void* d_ws, size_t ws_size,
                              hipStream_t stream) {
    const float* q_data = (const float*)d_in[0];
    const float* m_data = (const float*)d_in[1];
    const float* bias   = (const float*)d_in[2];
    const float* nbias  = (const float*)d_in[3];
    const float* q_w    = (const float*)d_in[4];
    const float* k_w    = (const float*)d_in[5];
    const float* v_w    = (const float*)d_in[6];
    const float* o_w    = (const float*)d_in[7];
    const float* o_b    = (const float*)d_in[8];
    const float* g_w    = (const float*)d_in[9];
    const float* g_b    = (const float*)d_in[10];
    float* out = (float*)d_out;

    const size_t MB = (size_t)NB * SQ * DM * 2;
    char* ws = (char*)d_ws;
    u16* qb    = (u16*)(ws);
    u16* kb    = (u16*)(ws + MB);
    u16* vTb   = (u16*)(ws + 2 * MB);
    u16* gateb = (u16*)(ws + 3 * MB);
    u16* wavg  = (u16*)(ws + 4 * MB);
    float* nb2 = (float*)(ws + 5 * MB + 655360);  // 4.7MB

    proj01_kernel<<<1056, 256, 0, stream>>>(q_data, m_data, q_w, g_w, k_w, v_w,
                                            g_b, nbias, qb, gateb, kb, vTb, nb2);

    const int ATTN_SMEM = 2 * 24576;  // 48 KB
    hipFuncSetAttribute((const void*)attn_kernel,
                        hipFuncAttributeMaxDynamicSharedMemorySize, ATTN_SMEM);
    attn_kernel<<<1536, 256, ATTN_SMEM, stream>>>(qb, kb, vTb, gateb, bias, nb2, wavg);

    out_proj_kernel<<<384, 256, 0, stream>>>(wavg, o_w, o_b, out);
}

// Round 21
// 233.087 us; speedup vs baseline: 1.1530x; 1.1530x over previous
//
#include <hip/hip_runtime.h>
#include <hip/hip_bf16.h>

#define DM 256
#define NB 128
#define SQ 384
#define SK 384

typedef __bf16 bf16x4 __attribute__((ext_vector_type(4)));
typedef __bf16 bf16x8 __attribute__((ext_vector_type(8)));
typedef float f32x4 __attribute__((ext_vector_type(4)));
typedef unsigned short u16;
typedef unsigned int u32;

union BF8 { bf16x8 v8; bf16x4 v4[2]; uint2 u2[2]; };

__device__ __forceinline__ u16 f2bf(float f) {
    union { float fv; u32 u; } v; v.fv = f;
    u32 r = v.u + 0x7FFFu + ((v.u >> 16) & 1u);
    return (u16)(r >> 16);
}
__device__ __forceinline__ float bf2f(u16 u) {
    union { u32 v; float f; } x; x.v = ((u32)u) << 16; return x.f;
}
__device__ __forceinline__ uint2 pack4(float a, float b, float c, float d) {
    uint2 r;
    r.x = (u32)f2bf(a) | ((u32)f2bf(b) << 16);
    r.y = (u32)f2bf(c) | ((u32)f2bf(d) << 16);
    return r;
}
__device__ __forceinline__ uint2 pack4c(f32x4 v) {
    bf16x4 t;
    t[0] = (__bf16)v[0]; t[1] = (__bf16)v[1];
    t[2] = (__bf16)v[2]; t[3] = (__bf16)v[3];
    union { bf16x4 b; uint2 u; } cv; cv.b = t; return cv.u;
}
// async global->LDS, 16B per lane; LDS dest = wave-uniform base + lane*16
__device__ __forceinline__ void glds16(const void* g, void* l) {
    __builtin_amdgcn_global_load_lds(
        (const __attribute__((address_space(1))) unsigned int*)g,
        (__attribute__((address_space(3))) unsigned int*)l, 16, 0, 0);
}

// ---------------------------------------------------------------------------
// prep_w: W[k][n] fp32 -> Wt[n][k] bf16, one-shot COALESCED transpose pass
// (R20 lesson: inlining this per-slab scatters the loads; keep it separate).
// q_w gets scale*log2(e) folded.
// ---------------------------------------------------------------------------
__global__ __launch_bounds__(256)
void prep_w(const float* __restrict__ q_w, const float* __restrict__ k_w,
            const float* __restrict__ v_w, const float* __restrict__ g_w,
            const float* __restrict__ o_w, u16* __restrict__ wt)
{
    __shared__ float t[64][65];
    const int mat = blockIdx.z;
    const float* src = mat == 0 ? q_w : mat == 1 ? k_w : mat == 2 ? v_w : mat == 3 ? g_w : o_w;
    const float scale = (mat == 0) ? (float)(0.17677669529663687 * 1.4426950408889634) : 1.0f;
    const int k0 = blockIdx.x * 64, n0 = blockIdx.y * 64;
    const int tid = threadIdx.x;
#pragma unroll
    for (int i = 0; i < 4; ++i) {
        int pos = tid + i * 256;
        int r = pos >> 4, c4 = (pos & 15) * 4;
        f32x4 v = *(const f32x4*)&src[(size_t)(k0 + r) * DM + n0 + c4];
        t[r][c4 + 0] = v[0]; t[r][c4 + 1] = v[1]; t[r][c4 + 2] = v[2]; t[r][c4 + 3] = v[3];
    }
    __syncthreads();
    const int nr = tid >> 2, kq = (tid & 3) * 16;
    u16* dst = wt + (size_t)mat * DM * DM + (size_t)(n0 + nr) * DM + k0 + kq;
#pragma unroll
    for (int j = 0; j < 16; j += 4) {
        uint2 p = pack4(t[kq + j][nr] * scale, t[kq + j + 1][nr] * scale,
                        t[kq + j + 2][nr] * scale, t[kq + j + 3][nr] * scale);
        *(uint2*)&dst[j] = p;
    }
}

// ---------------------------------------------------------------------------
// proj01_kernel: MERGED proj<0> + proj<1> + prep_nb in one launch.
// blocks 0..383:   mode 0 (q/gate from q_data via Wtq/Wtg)
// blocks 384..767: mode 1 (k/v from m_data via Wtk/Wtv, permuted outputs)
// blocks 768..1055: nb2 = nbias*log2e - 20 (elementwise tail)
// M-tile 128 (two 64-row groups share each staged W slab).
// ---------------------------------------------------------------------------
__global__ __launch_bounds__(256)
void proj01_kernel(const float* __restrict__ Aq, const float* __restrict__ Am,
                   const u16* __restrict__ Wtq, const u16* __restrict__ Wtg,
                   const u16* __restrict__ Wtk, const u16* __restrict__ Wtv,
                   const float* __restrict__ gb, const float* __restrict__ nbias,
                   u16* __restrict__ qb, u16* __restrict__ gateb,
                   u16* __restrict__ kb, u16* __restrict__ vT,
                   float* __restrict__ nb2)
{
    const int bx = blockIdx.x;
    const int tid = threadIdx.x;
    if (bx >= 768) {
        const size_t base = ((size_t)(bx - 768) * 256 + tid) * 16;
#pragma unroll
        for (int i = 0; i < 4; ++i) {
            f32x4 v = *(const f32x4*)&nbias[base + i * 4];
            *(f32x4*)&nb2[base + i * 4] = v * 1.4426950408889634f - 20.0f;
        }
        return;
    }
    const int mode = bx >= 384;
    const int m0 = (mode ? bx - 384 : bx) * 128;
    const float* Af = mode ? Am : Aq;
    const u16* W1 = mode ? Wtk : Wtq;
    const u16* W2 = mode ? Wtv : Wtg;

    __shared__ u16 Wlds[64 * 256];
    const int lane = tid & 63, w = tid >> 6;
    const int lr = lane & 15, lg = lane >> 4;

    BF8 af0[8], af1[8];
    {
        const float* ar0 = Af + (size_t)(m0 + w * 16 + lr) * DM + 4 * lg;
        const float* ar1 = ar0 + (size_t)64 * DM;
#pragma unroll
        for (int ks = 0; ks < 8; ++ks) {
            f32x4 v0 = *(const f32x4*)&ar0[ks * 32];
            f32x4 v1 = *(const f32x4*)&ar0[ks * 32 + 16];
            af0[ks].u2[0] = pack4(v0[0], v0[1], v0[2], v0[3]);
            af0[ks].u2[1] = pack4(v1[0], v1[1], v1[2], v1[3]);
            f32x4 w0 = *(const f32x4*)&ar1[ks * 32];
            f32x4 w1 = *(const f32x4*)&ar1[ks * 32 + 16];
            af1[ks].u2[0] = pack4(w0[0], w0[1], w0[2], w0[3]);
            af1[ks].u2[1] = pack4(w1[0], w1[1], w1[2], w1[3]);
        }
    }

    for (int sl = 0; sl < 8; ++sl) {
        const u16* Wsrc = (sl < 4) ? W1 : W2;
        const int n0 = (sl & 3) * 64;
        if (sl) __syncthreads();
#pragma unroll
        for (int i = 0; i < 8; ++i) {
            int pos = tid + i * 256;
            int nr = pos >> 5, c8 = (pos & 31) * 8;
            uint4 gv = *(const uint4*)&Wsrc[(size_t)(n0 + nr) * DM + c8];
            int within = c8 & 31;
            int pa2 = (c8 >> 5) * 64 + ((within >> 3) & 1) * 32 + (within >> 4) * 8;
            int sw = (nr & 7) << 4;
            char* rb_ = (char*)Wlds + nr * 512;
            *(uint2*)(rb_ + (pa2 ^ sw)) = make_uint2(gv.x, gv.y);
            *(uint2*)(rb_ + ((pa2 + 16) ^ sw)) = make_uint2(gv.z, gv.w);
        }
        __syncthreads();

        f32x4 acc0[4], acc1[4];
#pragma unroll
        for (int nf = 0; nf < 4; ++nf) {
            acc0[nf] = (f32x4){0.f, 0.f, 0.f, 0.f};
            acc1[nf] = (f32x4){0.f, 0.f, 0.f, 0.f};
        }
#pragma unroll
        for (int ks = 0; ks < 8; ++ks) {
#pragma unroll
            for (int nf = 0; nf < 4; ++nf) {
                int row = nf * 16 + lr;
                bf16x8 bfr = *(const bf16x8*)((char*)Wlds + row * 512 +
                                              ((ks * 64 + lg * 16) ^ ((row & 7) << 4)));
                acc0[nf] = __builtin_amdgcn_mfma_f32_16x16x32_bf16(af0[ks].v8, bfr, acc0[nf], 0, 0, 0);
                acc1[nf] = __builtin_amdgcn_mfma_f32_16x16x32_bf16(af1[ks].v8, bfr, acc1[nf], 0, 0, 0);
            }
        }

#pragma unroll
        for (int rg = 0; rg < 2; ++rg) {
            const int mb = m0 + rg * 64;
#pragma unroll
            for (int nf = 0; nf < 4; ++nf) {
                f32x4 accv = rg ? acc1[nf] : acc0[nf];
                int n = n0 + nf * 16 + lr;
                int gn = (sl & 3) * 64 + nf * 16 + lr;
                if (mode == 0) {
                    if (sl < 4) {
#pragma unroll
                        for (int r = 0; r < 4; ++r)
                            qb[(size_t)(mb + w * 16 + 4 * lg + r) * DM + n] = f2bf(accv[r]);
                    } else {
                        float gbv = gb[gn];
#pragma unroll
                        for (int r = 0; r < 4; ++r)
                            gateb[(size_t)(mb + w * 16 + 4 * lg + r) * DM + gn] =
                                f2bf(1.f / (1.f + __expf(-(accv[r] + gbv))));
                    }
                } else {
                    if (sl < 4) {
                        int pn = (n & ~31) | (((n >> 2) & 3) << 3) | (((n >> 4) & 1) << 2) | (n & 3);
#pragma unroll
                        for (int r = 0; r < 4; ++r)
                            kb[(size_t)(mb + w * 16 + 4 * lg + r) * DM + pn] = f2bf(accv[r]);
                    } else {
                        int bb = mb / SQ;
                        int kkl = mb - bb * SQ + w * 16 + 4 * lg;
                        int cc = kkl & 31;
                        int kkp = (kkl & ~31) | (((cc >> 2) & 3) << 3) | (((cc >> 4) & 1) << 2);
                        *(uint2*)&vT[(size_t)(bb * DM + gn) * SK + kkp] =
                            pack4(accv[0], accv[1], accv[2], accv[3]);
                    }
                }
            }
        }
    }
}

// ---------------------------------------------------------------------------
// out_proj (M-tile 128): out = wavg @ o_w + o_b (Wto bf16 pre-transposed)
// ---------------------------------------------------------------------------
__global__ __launch_bounds__(256)
void out_proj_kernel(const u16* __restrict__ Abf, const u16* __restrict__ Wto,
                     const float* __restrict__ ob, float* __restrict__ outf)
{
    __shared__ u16 Wlds[64 * 256];
    const int tid = threadIdx.x, lane = tid & 63, w = tid >> 6;
    const int lr = lane & 15, lg = lane >> 4;
    const int m0 = blockIdx.x * 128;

    BF8 af0[8], af1[8];
    {
        const u16* ar0 = Abf + (size_t)(m0 + w * 16 + lr) * DM + 4 * lg;
        const u16* ar1 = ar0 + (size_t)64 * DM;
#pragma unroll
        for (int ks = 0; ks < 8; ++ks) {
            af0[ks].u2[0] = *(const uint2*)&ar0[ks * 32];
            af0[ks].u2[1] = *(const uint2*)&ar0[ks * 32 + 16];
            af1[ks].u2[0] = *(const uint2*)&ar1[ks * 32];
            af1[ks].u2[1] = *(const uint2*)&ar1[ks * 32 + 16];
        }
    }

    for (int sl = 0; sl < 4; ++sl) {
        const int n0 = sl * 64;
        if (sl) __syncthreads();
#pragma unroll
        for (int i = 0; i < 8; ++i) {
            int pos = tid + i * 256;
            int nr = pos >> 5, c8 = (pos & 31) * 8;
            uint4 gv = *(const uint4*)&Wto[(size_t)(n0 + nr) * DM + c8];
            int within = c8 & 31;
            int pa2 = (c8 >> 5) * 64 + ((within >> 3) & 1) * 32 + (within >> 4) * 8;
            int sw = (nr & 7) << 4;
            char* rb_ = (char*)Wlds + nr * 512;
            *(uint2*)(rb_ + (pa2 ^ sw)) = make_uint2(gv.x, gv.y);
            *(uint2*)(rb_ + ((pa2 + 16) ^ sw)) = make_uint2(gv.z, gv.w);
        }
        __syncthreads();

        f32x4 acc0[4], acc1[4];
#pragma unroll
        for (int nf = 0; nf < 4; ++nf) {
            acc0[nf] = (f32x4){0.f, 0.f, 0.f, 0.f};
            acc1[nf] = (f32x4){0.f, 0.f, 0.f, 0.f};
        }
#pragma unroll
        for (int ks = 0; ks < 8; ++ks) {
#pragma unroll
            for (int nf = 0; nf < 4; ++nf) {
                int row = nf * 16 + lr;
                bf16x8 bfr = *(const bf16x8*)((char*)Wlds + row * 512 +
                                              ((ks * 64 + lg * 16) ^ ((row & 7) << 4)));
                acc0[nf] = __builtin_amdgcn_mfma_f32_16x16x32_bf16(af0[ks].v8, bfr, acc0[nf], 0, 0, 0);
                acc1[nf] = __builtin_amdgcn_mfma_f32_16x16x32_bf16(af1[ks].v8, bfr, acc1[nf], 0, 0, 0);
            }
        }

#pragma unroll
        for (int rg = 0; rg < 2; ++rg) {
            const int mb = m0 + rg * 64;
#pragma unroll
            for (int nf = 0; nf < 4; ++nf) {
                f32x4 accv = rg ? acc1[nf] : acc0[nf];
                int n = n0 + nf * 16 + lr;
                float obv = ob[n];
#pragma unroll
                for (int r = 0; r < 4; ++r)
                    outf[(size_t)(mb + w * 16 + 4 * lg + r) * DM + n] = accv[r] + obv;
            }
        }
    }
}

// ---------------------------------------------------------------------------
// attn (frozen): 256-thr blocks (4 waves = 4 heads), chunked-XCD swizzle,
// block = (qt, b, hg). Buffers K 8K + V 8K + bias 8K = 24KB, dbuf 48KB.
// gload_lds staging with source-side inverse swizzle (producer-permuted
// kb/vT), nbias first (FIFO), fixed-max exp2 softmax, deferred lsum.
// ---------------------------------------------------------------------------
__global__ __launch_bounds__(256, 1)
void attn_kernel(const u16* __restrict__ Qb, const u16* __restrict__ Kb,
                 const u16* __restrict__ vT, const u16* __restrict__ gateb,
                 const float* __restrict__ bias, const float* __restrict__ nb2,
                 u16* __restrict__ wavg)
{
    extern __shared__ char smem[];   // 2 x 24576: K 8K | V 8K | bias 8K
    const int tid = threadIdx.x, lane = tid & 63, hw = tid >> 6;
    const int lr = lane & 15, lg = lane >> 4;
    const int bid0 = blockIdx.x;
    const int bid = (bid0 & 7) * 192 + (bid0 >> 3);
    const int pair = bid >> 1, hg = bid & 1;
    const int qt = pair >> 7, b = pair & 127;   // qt-major
    const int q0 = qt * 64;
    const int h = hg * 4 + hw;
    const float LOG2E = 1.4426950408889634f;

    const int ciA = hw * 64 + lane, ciB = 256 + hw * 64 + lane;
    const int krA = ciA >> 4, kjA = (ciA & 15) ^ (krA & 7);
    const int krB = ciB >> 4, kjB = (ciB & 15) ^ (krB & 7);
    const u16* kgA = Kb + ((size_t)b * SK + krA) * DM + hg * 128 + kjA * 8;
    const u16* kgB = Kb + ((size_t)b * SK + krB) * DM + hg * 128 + kjB * 8;
    const int vrA = ciA >> 2, vjA = (ciA & 3) ^ ((vrA >> 1) & 3);
    const int vrB = ciB >> 2, vjB = (ciB & 3) ^ ((vrB >> 1) & 3);
    const u16* vgA = vT + ((size_t)b * DM + hg * 128 + vrA) * SK + vjA * 8;
    const u16* vgB = vT + ((size_t)b * DM + hg * 128 + vrB) * SK + vjB * 8;
    const int bqA = ciA >> 3, bjA = (ciA & 7) ^ (bqA & 7);
    const int bqB = ciB >> 3, bjB = (ciB & 7) ^ (bqB & 7);
    const float* bgA = bias + ((size_t)b * SQ + q0 + bqA) * SK + bjA * 4;
    const float* bgB = bias + ((size_t)b * SQ + q0 + bqB) * SK + bjB * 4;

    const int dA = hw * 1024, dB = 4096 + hw * 1024;

    BF8 qf[4];
    {
        const u16* qp = Qb + (size_t)(b * SQ + q0 + lr) * DM + h * 32 + 4 * lg;
#pragma unroll
        for (int nf = 0; nf < 4; ++nf) {
            qf[nf].u2[0] = *(const uint2*)&qp[nf * 16 * DM];
            qf[nf].u2[1] = *(const uint2*)&qp[nf * 16 * DM + 16];
        }
    }

    f32x4 Oacc[2][4];
    float lsum[4];
#pragma unroll
    for (int nf = 0; nf < 4; ++nf) {
        lsum[nf] = 0.f;
        Oacc[0][nf] = (f32x4){0.f, 0.f, 0.f, 0.f};
        Oacc[1][nf] = (f32x4){0.f, 0.f, 0.f, 0.f};
    }

    const float* np = nb2 + ((size_t)h * SQ + q0) * SK + 4 * lg;

    auto stage = [&](char* buf) {
        glds16(kgA, buf + dA); glds16(kgB, buf + dB);
        glds16(vgA, buf + 8192 + dA); glds16(vgB, buf + 8192 + dB);
        glds16(bgA, buf + 16384 + dA); glds16(bgB, buf + 16384 + dB);
        kgA += 32 * DM; kgB += 32 * DM; vgA += 32; vgB += 32; bgA += 32; bgB += 32;
    };

    stage(smem);
    asm volatile("s_waitcnt vmcnt(0)" ::: "memory");
    __builtin_amdgcn_s_barrier();

    int cur = 0;
#pragma unroll 1
    for (int kb = 0; kb < 12; ++kb) {
        const int k0 = kb * 32;
        char* buf = smem + cur * 24576;
        char* Kc = buf; char* Vc = buf + 8192; char* Bc = buf + 16384;

        f32x4 n4r[4][2];
#pragma unroll
        for (int nf = 0; nf < 4; ++nf)
#pragma unroll
            for (int rb = 0; rb < 2; ++rb)
                n4r[nf][rb] = *(const f32x4*)&np[(size_t)(nf * 16 + lr) * SK + k0 + rb * 16];
        __builtin_amdgcn_sched_barrier(0);

        if (kb < 11) stage(smem + (cur ^ 1) * 24576);

        f32x4 st[4][2];
        __builtin_amdgcn_s_setprio(1);
#pragma unroll
        for (int nf = 0; nf < 4; ++nf)
#pragma unroll
            for (int rb = 0; rb < 2; ++rb) {
                bf16x8 kfr = *(const bf16x8*)(Kc + (rb * 16 + lr) * 256 +
                                              (((hw * 4 + lg) ^ (lr & 7)) << 4));
                st[nf][rb] = __builtin_amdgcn_mfma_f32_16x16x32_bf16(
                    kfr, qf[nf].v8, (f32x4){0.f, 0.f, 0.f, 0.f}, 0, 0, 0);
            }
        __builtin_amdgcn_s_setprio(0);

        BF8 pvv[4];
#pragma unroll
        for (int nf = 0; nf < 4; ++nf)
#pragma unroll
            for (int rb = 0; rb < 2; ++rb) {
                f32x4 b4 = *(const f32x4*)(Bc + (nf * 16 + lr) * 128 +
                                           (((rb * 4 + lg) ^ (lr & 7)) << 4));
                f32x4 s = st[nf][rb] + b4 * LOG2E + n4r[nf][rb];
                f32x4 e;
                e[0] = __builtin_amdgcn_exp2f(s[0]);
                e[1] = __builtin_amdgcn_exp2f(s[1]);
                e[2] = __builtin_amdgcn_exp2f(s[2]);
                e[3] = __builtin_amdgcn_exp2f(s[3]);
                lsum[nf] += (e[0] + e[1]) + (e[2] + e[3]);
                pvv[nf].u2[rb] = pack4c(e);
            }

        __builtin_amdgcn_s_setprio(1);
#pragma unroll
        for (int cf = 0; cf < 2; ++cf) {
            int row = hw * 32 + cf * 16 + lr;
            bf16x8 vfr = *(const bf16x8*)(Vc + row * 64 + ((lg ^ ((lr >> 1) & 3)) << 4));
#pragma unroll
            for (int nf = 0; nf < 4; ++nf)
                Oacc[cf][nf] = __builtin_amdgcn_mfma_f32_16x16x32_bf16(
                    vfr, pvv[nf].v8, Oacc[cf][nf], 0, 0, 0);
        }
        __builtin_amdgcn_s_setprio(0);

        if (kb < 11) {
            asm volatile("s_waitcnt vmcnt(0)" ::: "memory");
            __builtin_amdgcn_s_barrier();
            cur ^= 1;
        }
    }

#pragma unroll
    for (int nf = 0; nf < 4; ++nf) {
        lsum[nf] += __shfl_xor(lsum[nf], 16, 64);
        lsum[nf] += __shfl_xor(lsum[nf], 32, 64);
    }

#pragma unroll
    for (int nf = 0; nf < 4; ++nf) {
        float rl = 1.0f / lsum[nf];
        size_t qrow = (size_t)(b * SQ + q0 + nf * 16 + lr);
#pragma unroll
        for (int cf = 0; cf < 2; ++cf) {
            size_t idx = qrow * DM + h * 32 + cf * 16 + 4 * lg;
            uint2 g2 = *(const uint2*)&gateb[idx];
            float g0 = bf2f((u16)(g2.x & 0xffff)), g1 = bf2f((u16)(g2.x >> 16));
            float g2f = bf2f((u16)(g2.y & 0xffff)), g3 = bf2f((u16)(g2.y >> 16));
            f32x4 o = Oacc[cf][nf];
            *(uint2*)&wavg[idx] = pack4(o[0] * rl * g0, o[1] * rl * g1,
                                        o[2] * rl * g2f, o[3] * rl * g3);
        }
    }
}

// ---------------------------------------------------------------------------
extern "C" void kernel_launch(void* const* d_in, const int* in_sizes, int n_in,
                              void* d_out, int out_size, void* d_ws, size_t ws_size,
                              hipStream_t stream) {
    const float* q_data = (const float*)d_in[0];
    const float* m_data = (const float*)d_in[1];
    const float* bias   = (const float*)d_in[2];
    const float* nbias  = (const float*)d_in[3];
    const float* q_w    = (const float*)d_in[4];
    const float* k_w    = (const float*)d_in[5];
    const float* v_w    = (const float*)d_in[6];
    const float* o_w    = (const float*)d_in[7];
    const float* o_b    = (const float*)d_in[8];
    const float* g_w    = (const float*)d_in[9];
    const float* g_b    = (const float*)d_in[10];
    float* out = (float*)d_out;

    const size_t MB = (size_t)NB * SQ * DM * 2;
    char* ws = (char*)d_ws;
    u16* qb    = (u16*)(ws);
    u16* kb    = (u16*)(ws + MB);
    u16* vTb   = (u16*)(ws + 2 * MB);
    u16* gateb = (u16*)(ws + 3 * MB);
    u16* wavg  = (u16*)(ws + 4 * MB);
    u16* wt    = (u16*)(ws + 5 * MB);             // 5 x 128KB
    float* nb2 = (float*)(ws + 5 * MB + 655360);  // 4.7MB
    u16* Wtq = wt, *Wtk = wt + 65536, *Wtv = wt + 2 * 65536,
       *Wtg = wt + 3 * 65536, *Wto = wt + 4 * 65536;

    prep_w<<<dim3(4, 4, 5), 256, 0, stream>>>(q_w, k_w, v_w, g_w, o_w, wt);
    proj01_kernel<<<1056, 256, 0, stream>>>(q_data, m_data, Wtq, Wtg, Wtk, Wtv,
                                            g_b, nbias, qb, gateb, kb, vTb, nb2);

    const int ATTN_SMEM = 2 * 24576;  // 48 KB
    hipFuncSetAttribute((const void*)attn_kernel,
                        hipFuncAttributeMaxDynamicSharedMemorySize, ATTN_SMEM);
    attn_kernel<<<1536, 256, ATTN_SMEM, stream>>>(qb, kb, vTb, gateb, bias, nb2, wavg);

    out_proj_kernel<<<384, 256, 0, stream>>>(wavg, Wto, o_b, out);
}

// Round 22
// 231.340 us; speedup vs baseline: 1.1617x; 1.0076x over previous
//
#include <hip/hip_runtime.h>
#include <hip/hip_bf16.h>

#define DM 256
#define NB 128
#define SQ 384
#define SK 384

typedef __bf16 bf16x4 __attribute__((ext_vector_type(4)));
typedef __bf16 bf16x8 __attribute__((ext_vector_type(8)));
typedef float f32x4 __attribute__((ext_vector_type(4)));
typedef unsigned short u16;
typedef unsigned int u32;

union BF8 { bf16x8 v8; bf16x4 v4[2]; uint2 u2[2]; };

__device__ __forceinline__ u16 f2bf(float f) {
    union { float fv; u32 u; } v; v.fv = f;
    u32 r = v.u + 0x7FFFu + ((v.u >> 16) & 1u);
    return (u16)(r >> 16);
}
__device__ __forceinline__ float bf2f(u16 u) {
    union { u32 v; float f; } x; x.v = ((u32)u) << 16; return x.f;
}
__device__ __forceinline__ uint2 pack4(float a, float b, float c, float d) {
    uint2 r;
    r.x = (u32)f2bf(a) | ((u32)f2bf(b) << 16);
    r.y = (u32)f2bf(c) | ((u32)f2bf(d) << 16);
    return r;
}
__device__ __forceinline__ uint2 pack4c(f32x4 v) {
    bf16x4 t;
    t[0] = (__bf16)v[0]; t[1] = (__bf16)v[1];
    t[2] = (__bf16)v[2]; t[3] = (__bf16)v[3];
    union { bf16x4 b; uint2 u; } cv; cv.b = t; return cv.u;
}
// async global->LDS, 16B per lane; LDS dest = wave-uniform base + lane*16
__device__ __forceinline__ void glds16(const void* g, void* l) {
    __builtin_amdgcn_global_load_lds(
        (const __attribute__((address_space(1))) unsigned int*)g,
        (__attribute__((address_space(3))) unsigned int*)l, 16, 0, 0);
}

// ---------------------------------------------------------------------------
// prep_w: W[k][n] fp32 -> Wt[n][k] bf16, one-shot COALESCED transpose pass.
// q_w gets scale*log2(e) folded.
// ---------------------------------------------------------------------------
__global__ __launch_bounds__(256)
void prep_w(const float* __restrict__ q_w, const float* __restrict__ k_w,
            const float* __restrict__ v_w, const float* __restrict__ g_w,
            const float* __restrict__ o_w, u16* __restrict__ wt)
{
    __shared__ float t[64][65];
    const int mat = blockIdx.z;
    const float* src = mat == 0 ? q_w : mat == 1 ? k_w : mat == 2 ? v_w : mat == 3 ? g_w : o_w;
    const float scale = (mat == 0) ? (float)(0.17677669529663687 * 1.4426950408889634) : 1.0f;
    const int k0 = blockIdx.x * 64, n0 = blockIdx.y * 64;
    const int tid = threadIdx.x;
#pragma unroll
    for (int i = 0; i < 4; ++i) {
        int pos = tid + i * 256;
        int r = pos >> 4, c4 = (pos & 15) * 4;
        f32x4 v = *(const f32x4*)&src[(size_t)(k0 + r) * DM + n0 + c4];
        t[r][c4 + 0] = v[0]; t[r][c4 + 1] = v[1]; t[r][c4 + 2] = v[2]; t[r][c4 + 3] = v[3];
    }
    __syncthreads();
    const int nr = tid >> 2, kq = (tid & 3) * 16;
    u16* dst = wt + (size_t)mat * DM * DM + (size_t)(n0 + nr) * DM + k0 + kq;
#pragma unroll
    for (int j = 0; j < 16; j += 4) {
        uint2 p = pack4(t[kq + j][nr] * scale, t[kq + j + 1][nr] * scale,
                        t[kq + j + 2][nr] * scale, t[kq + j + 3][nr] * scale);
        *(uint2*)&dst[j] = p;
    }
}

// ---------------------------------------------------------------------------
// proj01_kernel: MERGED proj<0> + proj<1> + prep_nb in one launch.
// ---------------------------------------------------------------------------
__global__ __launch_bounds__(256)
void proj01_kernel(const float* __restrict__ Aq, const float* __restrict__ Am,
                   const u16* __restrict__ Wtq, const u16* __restrict__ Wtg,
                   const u16* __restrict__ Wtk, const u16* __restrict__ Wtv,
                   const float* __restrict__ gb, const float* __restrict__ nbias,
                   u16* __restrict__ qb, u16* __restrict__ gateb,
                   u16* __restrict__ kb, u16* __restrict__ vT,
                   float* __restrict__ nb2)
{
    const int bx = blockIdx.x;
    const int tid = threadIdx.x;
    if (bx >= 768) {
        const size_t base = ((size_t)(bx - 768) * 256 + tid) * 16;
#pragma unroll
        for (int i = 0; i < 4; ++i) {
            f32x4 v = *(const f32x4*)&nbias[base + i * 4];
            *(f32x4*)&nb2[base + i * 4] = v * 1.4426950408889634f - 20.0f;
        }
        return;
    }
    const int mode = bx >= 384;
    const int m0 = (mode ? bx - 384 : bx) * 128;
    const float* Af = mode ? Am : Aq;
    const u16* W1 = mode ? Wtk : Wtq;
    const u16* W2 = mode ? Wtv : Wtg;

    __shared__ u16 Wlds[64 * 256];
    const int lane = tid & 63, w = tid >> 6;
    const int lr = lane & 15, lg = lane >> 4;

    BF8 af0[8], af1[8];
    {
        const float* ar0 = Af + (size_t)(m0 + w * 16 + lr) * DM + 4 * lg;
        const float* ar1 = ar0 + (size_t)64 * DM;
#pragma unroll
        for (int ks = 0; ks < 8; ++ks) {
            f32x4 v0 = *(const f32x4*)&ar0[ks * 32];
            f32x4 v1 = *(const f32x4*)&ar0[ks * 32 + 16];
            af0[ks].u2[0] = pack4(v0[0], v0[1], v0[2], v0[3]);
            af0[ks].u2[1] = pack4(v1[0], v1[1], v1[2], v1[3]);
            f32x4 w0 = *(const f32x4*)&ar1[ks * 32];
            f32x4 w1 = *(const f32x4*)&ar1[ks * 32 + 16];
            af1[ks].u2[0] = pack4(w0[0], w0[1], w0[2], w0[3]);
            af1[ks].u2[1] = pack4(w1[0], w1[1], w1[2], w1[3]);
        }
    }

    for (int sl = 0; sl < 8; ++sl) {
        const u16* Wsrc = (sl < 4) ? W1 : W2;
        const int n0 = (sl & 3) * 64;
        if (sl) __syncthreads();
#pragma unroll
        for (int i = 0; i < 8; ++i) {
            int pos = tid + i * 256;
            int nr = pos >> 5, c8 = (pos & 31) * 8;
            uint4 gv = *(const uint4*)&Wsrc[(size_t)(n0 + nr) * DM + c8];
            int within = c8 & 31;
            int pa2 = (c8 >> 5) * 64 + ((within >> 3) & 1) * 32 + (within >> 4) * 8;
            int sw = (nr & 7) << 4;
            char* rb_ = (char*)Wlds + nr * 512;
            *(uint2*)(rb_ + (pa2 ^ sw)) = make_uint2(gv.x, gv.y);
            *(uint2*)(rb_ + ((pa2 + 16) ^ sw)) = make_uint2(gv.z, gv.w);
        }
        __syncthreads();

        f32x4 acc0[4], acc1[4];
#pragma unroll
        for (int nf = 0; nf < 4; ++nf) {
            acc0[nf] = (f32x4){0.f, 0.f, 0.f, 0.f};
            acc1[nf] = (f32x4){0.f, 0.f, 0.f, 0.f};
        }
#pragma unroll
        for (int ks = 0; ks < 8; ++ks) {
#pragma unroll
            for (int nf = 0; nf < 4; ++nf) {
                int row = nf * 16 + lr;
                bf16x8 bfr = *(const bf16x8*)((char*)Wlds + row * 512 +
                                              ((ks * 64 + lg * 16) ^ ((row & 7) << 4)));
                acc0[nf] = __builtin_amdgcn_mfma_f32_16x16x32_bf16(af0[ks].v8, bfr, acc0[nf], 0, 0, 0);
                acc1[nf] = __builtin_amdgcn_mfma_f32_16x16x32_bf16(af1[ks].v8, bfr, acc1[nf], 0, 0, 0);
            }
        }

#pragma unroll
        for (int rg = 0; rg < 2; ++rg) {
            const int mb = m0 + rg * 64;
#pragma unroll
            for (int nf = 0; nf < 4; ++nf) {
                f32x4 accv = rg ? acc1[nf] : acc0[nf];
                int n = n0 + nf * 16 + lr;
                int gn = (sl & 3) * 64 + nf * 16 + lr;
                if (mode == 0) {
                    if (sl < 4) {
#pragma unroll
                        for (int r = 0; r < 4; ++r)
                            qb[(size_t)(mb + w * 16 + 4 * lg + r) * DM + n] = f2bf(accv[r]);
                    } else {
                        float gbv = gb[gn];
#pragma unroll
                        for (int r = 0; r < 4; ++r)
                            gateb[(size_t)(mb + w * 16 + 4 * lg + r) * DM + gn] =
                                f2bf(1.f / (1.f + __expf(-(accv[r] + gbv))));
                    }
                } else {
                    if (sl < 4) {
                        int pn = (n & ~31) | (((n >> 2) & 3) << 3) | (((n >> 4) & 1) << 2) | (n & 3);
#pragma unroll
                        for (int r = 0; r < 4; ++r)
                            kb[(size_t)(mb + w * 16 + 4 * lg + r) * DM + pn] = f2bf(accv[r]);
                    } else {
                        int bb = mb / SQ;
                        int kkl = mb - bb * SQ + w * 16 + 4 * lg;
                        int cc = kkl & 31;
                        int kkp = (kkl & ~31) | (((cc >> 2) & 3) << 3) | (((cc >> 4) & 1) << 2);
                        *(uint2*)&vT[(size_t)(bb * DM + gn) * SK + kkp] =
                            pack4(accv[0], accv[1], accv[2], accv[3]);
                    }
                }
            }
        }
    }
}

// ---------------------------------------------------------------------------
// out_proj (M-tile 128): out = wavg @ o_w + o_b
// ---------------------------------------------------------------------------
__global__ __launch_bounds__(256)
void out_proj_kernel(const u16* __restrict__ Abf, const u16* __restrict__ Wto,
                     const float* __restrict__ ob, float* __restrict__ outf)
{
    __shared__ u16 Wlds[64 * 256];
    const int tid = threadIdx.x, lane = tid & 63, w = tid >> 6;
    const int lr = lane & 15, lg = lane >> 4;
    const int m0 = blockIdx.x * 128;

    BF8 af0[8], af1[8];
    {
        const u16* ar0 = Abf + (size_t)(m0 + w * 16 + lr) * DM + 4 * lg;
        const u16* ar1 = ar0 + (size_t)64 * DM;
#pragma unroll
        for (int ks = 0; ks < 8; ++ks) {
            af0[ks].u2[0] = *(const uint2*)&ar0[ks * 32];
            af0[ks].u2[1] = *(const uint2*)&ar0[ks * 32 + 16];
            af1[ks].u2[0] = *(const uint2*)&ar1[ks * 32];
            af1[ks].u2[1] = *(const uint2*)&ar1[ks * 32 + 16];
        }
    }

    for (int sl = 0; sl < 4; ++sl) {
        const int n0 = sl * 64;
        if (sl) __syncthreads();
#pragma unroll
        for (int i = 0; i < 8; ++i) {
            int pos = tid + i * 256;
            int nr = pos >> 5, c8 = (pos & 31) * 8;
            uint4 gv = *(const uint4*)&Wto[(size_t)(n0 + nr) * DM + c8];
            int within = c8 & 31;
            int pa2 = (c8 >> 5) * 64 + ((within >> 3) & 1) * 32 + (within >> 4) * 8;
            int sw = (nr & 7) << 4;
            char* rb_ = (char*)Wlds + nr * 512;
            *(uint2*)(rb_ + (pa2 ^ sw)) = make_uint2(gv.x, gv.y);
            *(uint2*)(rb_ + ((pa2 + 16) ^ sw)) = make_uint2(gv.z, gv.w);
        }
        __syncthreads();

        f32x4 acc0[4], acc1[4];
#pragma unroll
        for (int nf = 0; nf < 4; ++nf) {
            acc0[nf] = (f32x4){0.f, 0.f, 0.f, 0.f};
            acc1[nf] = (f32x4){0.f, 0.f, 0.f, 0.f};
        }
#pragma unroll
        for (int ks = 0; ks < 8; ++ks) {
#pragma unroll
            for (int nf = 0; nf < 4; ++nf) {
                int row = nf * 16 + lr;
                bf16x8 bfr = *(const bf16x8*)((char*)Wlds + row * 512 +
                                              ((ks * 64 + lg * 16) ^ ((row & 7) << 4)));
                acc0[nf] = __builtin_amdgcn_mfma_f32_16x16x32_bf16(af0[ks].v8, bfr, acc0[nf], 0, 0, 0);
                acc1[nf] = __builtin_amdgcn_mfma_f32_16x16x32_bf16(af1[ks].v8, bfr, acc1[nf], 0, 0, 0);
            }
        }

#pragma unroll
        for (int rg = 0; rg < 2; ++rg) {
            const int mb = m0 + rg * 64;
#pragma unroll
            for (int nf = 0; nf < 4; ++nf) {
                f32x4 accv = rg ? acc1[nf] : acc0[nf];
                int n = n0 + nf * 16 + lr;
                float obv = ob[n];
#pragma unroll
                for (int r = 0; r < 4; ++r)
                    outf[(size_t)(mb + w * 16 + 4 * lg + r) * DM + n] = accv[r] + obv;
            }
        }
    }
}

// ---------------------------------------------------------------------------
// attn R22: R21 4-wave pipeline + 3-BUFFER COUNTED-VMCNT prefetch (R14's
// proven protocol, ported to the faster 4-wave shape). Stage tile t+2
// during tile t; end-of-tile wait = vmcnt(6) so stage(t+2)'s 6 loads stay
// in flight across the barrier (2-tile prefetch depth ~1300cy > ~900cy
// cold-HBM latency of K/V stage loads). nbias(t)'s implicit wait (step 4)
// = vmcnt(6) drains stage(t+1) exactly when needed (FIFO). Buffer (t+2)%3
// last read in tile t-1 (completed before the barrier preceding issue).
// LDS 3 x 24KB = 72KB.
// ---------------------------------------------------------------------------
__global__ __launch_bounds__(256, 1)
void attn_kernel(const u16* __restrict__ Qb, const u16* __restrict__ Kb,
                 const u16* __restrict__ vT, const u16* __restrict__ gateb,
                 const float* __restrict__ bias, const float* __restrict__ nb2,
                 u16* __restrict__ wavg)
{
    extern __shared__ char smem[];   // 3 x 24576: K 8K | V 8K | bias 8K
    const int tid = threadIdx.x, lane = tid & 63, hw = tid >> 6;
    const int lr = lane & 15, lg = lane >> 4;
    const int bid0 = blockIdx.x;
    const int bid = (bid0 & 7) * 192 + (bid0 >> 3);
    const int pair = bid >> 1, hg = bid & 1;
    const int qt = pair >> 7, b = pair & 127;   // qt-major
    const int q0 = qt * 64;
    const int h = hg * 4 + hw;
    const float LOG2E = 1.4426950408889634f;

    const int ciA = hw * 64 + lane, ciB = 256 + hw * 64 + lane;
    const int krA = ciA >> 4, kjA = (ciA & 15) ^ (krA & 7);
    const int krB = ciB >> 4, kjB = (ciB & 15) ^ (krB & 7);
    const u16* kgA = Kb + ((size_t)b * SK + krA) * DM + hg * 128 + kjA * 8;
    const u16* kgB = Kb + ((size_t)b * SK + krB) * DM + hg * 128 + kjB * 8;
    const int vrA = ciA >> 2, vjA = (ciA & 3) ^ ((vrA >> 1) & 3);
    const int vrB = ciB >> 2, vjB = (ciB & 3) ^ ((vrB >> 1) & 3);
    const u16* vgA = vT + ((size_t)b * DM + hg * 128 + vrA) * SK + vjA * 8;
    const u16* vgB = vT + ((size_t)b * DM + hg * 128 + vrB) * SK + vjB * 8;
    const int bqA = ciA >> 3, bjA = (ciA & 7) ^ (bqA & 7);
    const int bqB = ciB >> 3, bjB = (ciB & 7) ^ (bqB & 7);
    const float* bgA = bias + ((size_t)b * SQ + q0 + bqA) * SK + bjA * 4;
    const float* bgB = bias + ((size_t)b * SQ + q0 + bqB) * SK + bjB * 4;

    const int dA = hw * 1024, dB = 4096 + hw * 1024;

    BF8 qf[4];
    {
        const u16* qp = Qb + (size_t)(b * SQ + q0 + lr) * DM + h * 32 + 4 * lg;
#pragma unroll
        for (int nf = 0; nf < 4; ++nf) {
            qf[nf].u2[0] = *(const uint2*)&qp[nf * 16 * DM];
            qf[nf].u2[1] = *(const uint2*)&qp[nf * 16 * DM + 16];
        }
    }

    f32x4 Oacc[2][4];
    float lsum[4];
#pragma unroll
    for (int nf = 0; nf < 4; ++nf) {
        lsum[nf] = 0.f;
        Oacc[0][nf] = (f32x4){0.f, 0.f, 0.f, 0.f};
        Oacc[1][nf] = (f32x4){0.f, 0.f, 0.f, 0.f};
    }

    const float* np = nb2 + ((size_t)h * SQ + q0) * SK + 4 * lg;

    auto stage = [&](char* buf) {
        glds16(kgA, buf + dA); glds16(kgB, buf + dB);
        glds16(vgA, buf + 8192 + dA); glds16(vgB, buf + 8192 + dB);
        glds16(bgA, buf + 16384 + dA); glds16(bgB, buf + 16384 + dB);
        kgA += 32 * DM; kgB += 32 * DM; vgA += 32; vgB += 32; bgA += 32; bgB += 32;
    };

    // prologue: stage tiles 0 and 1; wait for tile 0 only (6 newest in flight)
    stage(smem);
    stage(smem + 24576);
    asm volatile("s_waitcnt vmcnt(6)" ::: "memory");
    __builtin_amdgcn_s_barrier();

#pragma unroll 1
    for (int kb = 0; kb < 12; ++kb) {
        const int k0 = kb * 32;
        char* buf = smem + (kb % 3) * 24576;
        char* Kc = buf; char* Vc = buf + 8192; char* Bc = buf + 16384;

        // 1. nbias loads FIRST; their implicit wait (step 4) = vmcnt(6),
        //    draining stage(kb+1) while stage(kb+2) stays outstanding.
        f32x4 n4r[4][2];
#pragma unroll
        for (int nf = 0; nf < 4; ++nf)
#pragma unroll
            for (int rb = 0; rb < 2; ++rb)
                n4r[nf][rb] = *(const f32x4*)&np[(size_t)(nf * 16 + lr) * SK + k0 + rb * 16];
        __builtin_amdgcn_sched_barrier(0);

        // 2. issue stage(kb+2) into buf[(kb+2)%3] (free since end of kb-1)
        if (kb < 10) stage(smem + ((kb + 2) % 3) * 24576);

        // 3. QK: S^T = K @ Q^T with C=0
        f32x4 st[4][2];
        __builtin_amdgcn_s_setprio(1);
#pragma unroll
        for (int nf = 0; nf < 4; ++nf)
#pragma unroll
            for (int rb = 0; rb < 2; ++rb) {
                bf16x8 kfr = *(const bf16x8*)(Kc + (rb * 16 + lr) * 256 +
                                              (((hw * 4 + lg) ^ (lr & 7)) << 4));
                st[nf][rb] = __builtin_amdgcn_mfma_f32_16x16x32_bf16(
                    kfr, qf[nf].v8, (f32x4){0.f, 0.f, 0.f, 0.f}, 0, 0, 0);
            }
        __builtin_amdgcn_s_setprio(0);

        // 4. biases + exp2 + pack + per-lane lsum
        BF8 pvv[4];
#pragma unroll
        for (int nf = 0; nf < 4; ++nf)
#pragma unroll
            for (int rb = 0; rb < 2; ++rb) {
                f32x4 b4 = *(const f32x4*)(Bc + (nf * 16 + lr) * 128 +
                                           (((rb * 4 + lg) ^ (lr & 7)) << 4));
                f32x4 s = st[nf][rb] + b4 * LOG2E + n4r[nf][rb];
                f32x4 e;
                e[0] = __builtin_amdgcn_exp2f(s[0]);
                e[1] = __builtin_amdgcn_exp2f(s[1]);
                e[2] = __builtin_amdgcn_exp2f(s[2]);
                e[3] = __builtin_amdgcn_exp2f(s[3]);
                lsum[nf] += (e[0] + e[1]) + (e[2] + e[3]);
                pvv[nf].u2[rb] = pack4c(e);
            }

        // 5. PV: O^T += V^T @ P^T
        __builtin_amdgcn_s_setprio(1);
#pragma unroll
        for (int cf = 0; cf < 2; ++cf) {
            int row = hw * 32 + cf * 16 + lr;
            bf16x8 vfr = *(const bf16x8*)(Vc + row * 64 + ((lg ^ ((lr >> 1) & 3)) << 4));
#pragma unroll
            for (int nf = 0; nf < 4; ++nf)
                Oacc[cf][nf] = __builtin_amdgcn_mfma_f32_16x16x32_bf16(
                    vfr, pvv[nf].v8, Oacc[cf][nf], 0, 0, 0);
        }
        __builtin_amdgcn_s_setprio(0);

        // 6. counted wait: stage(kb+1) resident; stage(kb+2) stays in flight
        if (kb < 10)       asm volatile("s_waitcnt vmcnt(6)" ::: "memory");
        else if (kb == 10) asm volatile("s_waitcnt vmcnt(0)" ::: "memory");
        if (kb < 11) __builtin_amdgcn_s_barrier();
    }

#pragma unroll
    for (int nf = 0; nf < 4; ++nf) {
        lsum[nf] += __shfl_xor(lsum[nf], 16, 64);
        lsum[nf] += __shfl_xor(lsum[nf], 32, 64);
    }

#pragma unroll
    for (int nf = 0; nf < 4; ++nf) {
        float rl = 1.0f / lsum[nf];
        size_t qrow = (size_t)(b * SQ + q0 + nf * 16 + lr);
#pragma unroll
        for (int cf = 0; cf < 2; ++cf) {
            size_t idx = qrow * DM + h * 32 + cf * 16 + 4 * lg;
            uint2 g2 = *(const uint2*)&gateb[idx];
            float g0 = bf2f((u16)(g2.x & 0xffff)), g1 = bf2f((u16)(g2.x >> 16));
            float g2f = bf2f((u16)(g2.y & 0xffff)), g3 = bf2f((u16)(g2.y >> 16));
            f32x4 o = Oacc[cf][nf];
            *(uint2*)&wavg[idx] = pack4(o[0] * rl * g0, o[1] * rl * g1,
                                        o[2] * rl * g2f, o[3] * rl * g3);
        }
    }
}

// ---------------------------------------------------------------------------
extern "C" void kernel_launch(void* const* d_in, const int* in_sizes, int n_in,
                              void* d_out, int out_size, void* d_ws, size_t ws_size,
                              hipStream_t stream) {
    const float* q_data = (const float*)d_in[0];
    const float* m_data = (const float*)d_in[1];
    const float* bias   = (const float*)d_in[2];
    const float* nbias  = (const float*)d_in[3];
    const float* q_w    = (const float*)d_in[4];
    const float* k_w    = (const float*)d_in[5];
    const float* v_w    = (const float*)d_in[6];
    const float* o_w    = (const float*)d_in[7];
    const float* o_b    = (const float*)d_in[8];
    const float* g_w    = (const float*)d_in[9];
    const float* g_b    = (const float*)d_in[10];
    float* out = (float*)d_out;

    const size_t MB = (size_t)NB * SQ * DM * 2;
    char* ws = (char*)d_ws;
    u16* qb    = (u16*)(ws);
    u16* kb    = (u16*)(ws + MB);
    u16* vTb   = (u16*)(ws + 2 * MB);
    u16* gateb = (u16*)(ws + 3 * MB);
    u16* wavg  = (u16*)(ws + 4 * MB);
    u16* wt    = (u16*)(ws + 5 * MB);             // 5 x 128KB
    float* nb2 = (float*)(ws + 5 * MB + 655360);  // 4.7MB
    u16* Wtq = wt, *Wtk = wt + 65536, *Wtv = wt + 2 * 65536,
       *Wtg = wt + 3 * 65536, *Wto = wt + 4 * 65536;

    prep_w<<<dim3(4, 4, 5), 256, 0, stream>>>(q_w, k_w, v_w, g_w, o_w, wt);
    proj01_kernel<<<1056, 256, 0, stream>>>(q_data, m_data, Wtq, Wtg, Wtk, Wtv,
                                            g_b, nbias, qb, gateb, kb, vTb, nb2);

    const int ATTN_SMEM = 3 * 24576;  // 72 KB, 3-buffer counted-vmcnt pipeline
    hipFuncSetAttribute((const void*)attn_kernel,
                        hipFuncAttributeMaxDynamicSharedMemorySize, ATTN_SMEM);
    attn_kernel<<<1536, 256, ATTN_SMEM, stream>>>(qb, kb, vTb, gateb, bias, nb2, wavg);

    out_proj_kernel<<<384, 256, 0, stream>>>(wavg, Wto, o_b, out);
}